// Round 7
// baseline (232.197 us; speedup 1.0000x reference)
//
#include <hip/hip_runtime.h>
#include <hip/hip_bf16.h>
#include <stdint.h>

// B=16, N=4096, H=512, K=2H=1024
//   pf[b,n,h]   = sum_k features[b,n,k] * Wf[h,k]
//   pq[b,h]     = sum_k query[b,k] * Wq[h,k]
//   logits[b,n] = 10*tanh( sum_h v[h]*tanh(pf+pq) )
// Outputs: pf (33554432 f32) then logits (65536 f32).
// R7: two-pass, zero-sync hot loops, sized for bytes-in-flight.
//  Pass 1 (acvt): features fp32 -> bf16 in MFMA-FRAGMENT order, written into
//    the pf region of d_out (exact 1:1 row aliasing: rows' bf16 fragments and
//    the rows' pf outputs occupy the same 131072B range per 64-row block; a
//    gemm block reads all its A before its epilogue overwrites it). Pure
//    streaming, no barriers -> HBM-saturating.
//  Pass 2 (gemm): NO LDS, NO barriers, NO cvt. A and B both pre-shuffled
//    bf16 fragments; every load is a coalesced 16B/lane reg load; 1-deep
//    ping-pong. 8 waves/CU x ~12KB in flight ~ 96KB/CU outstanding.
//    Wave-tile 64x128 (acc 128 AGPR), 4 waves/block n-split, 1024 blocks.

#define KDIM 1024
#define HDIM 512

typedef short bf16x8 __attribute__((ext_vector_type(8)));
typedef float f32x4  __attribute__((ext_vector_type(4)));

__device__ __forceinline__ float fast_tanh(float x) {
    float ax = fabsf(x);
    float e  = __expf(-2.0f * ax);
    float r  = (1.0f - e) / (1.0f + e);
    return copysignf(r, x);
}

__device__ __forceinline__ short f2bf(float x) {
    __hip_bfloat16 b = __float2bfloat16(x);
    return (short)__builtin_bit_cast(unsigned short, b);
}

__device__ __forceinline__ bf16x8 cvt8(float4 a, float4 b) {
    bf16x8 o;
    o[0] = f2bf(a.x); o[1] = f2bf(a.y); o[2] = f2bf(a.z); o[3] = f2bf(a.w);
    o[4] = f2bf(b.x); o[5] = f2bf(b.y); o[6] = f2bf(b.z); o[7] = f2bf(b.w);
    return o;
}

// ---------------- features -> bf16 A-fragment order ----------------
// chunk tid = ((rb*32 + kt)*4 + f)*64 + lane, lane = fkg*16 + fm:
// content = A[rb*64 + f*16 + fm][kt*32 + fkg*8 .. +8] as bf16x8.
__global__ void acvt_kernel(const float* __restrict__ A, short* __restrict__ Abf) {
    const int tid  = blockIdx.x * 256 + threadIdx.x;   // 8,388,608 threads
    const int lane = tid & 63;
    const int f    = (tid >> 6) & 3;
    const int kt   = (tid >> 8) & 31;
    const int rb   = tid >> 13;
    const int fm   = lane & 15, fkg = lane >> 4;
    const int row  = rb * 64 + f * 16 + fm;
    const int k0   = kt * 32 + fkg * 8;
    const float* src = A + (size_t)row * KDIM + k0;
    float4 a = *(const float4*)src;
    float4 b = *(const float4*)(src + 4);
    *(bf16x8*)(Abf + (size_t)tid * 8) = cvt8(a, b);
}

// ---------------- Wf -> bf16 B-fragment order (proven R4-R6) ----------------
// chunk tid = (kt*32 + gg)*64 + lane: content = Wf[gg*16+fm][kt*32+fkg*8..+8].
__global__ void bshuf_kernel(const float* __restrict__ Wf, short* __restrict__ Bsh) {
    const int tid = blockIdx.x * 256 + threadIdx.x;   // 0..65535
    const int kt  = tid >> 11;
    const int gg  = (tid >> 6) & 31;
    const int ln  = tid & 63;
    const int fm  = ln & 15, fkg = ln >> 4;
    const int col = gg * 16 + fm;
    const int k0  = kt * 32 + fkg * 8;
    const float* src = Wf + col * KDIM + k0;
    float4 a = *(const float4*)src;
    float4 b = *(const float4*)(src + 4);
    *(bf16x8*)(Bsh + (size_t)tid * 8) = cvt8(a, b);
}

// ---------------- tiny GEMM: pq[b,h] ----------------
__global__ void pq_kernel(const float* __restrict__ query,
                          const float* __restrict__ Wq,
                          float* __restrict__ pq) {
    const int t = blockIdx.x * blockDim.x + threadIdx.x;   // 8192
    const int b = t >> 9, h = t & 511;
    const float4* q  = (const float4*)(query + (b << 9));
    const float4* wq = (const float4*)(Wq + ((size_t)h << 9));
    float s = 0.0f;
    #pragma unroll 4
    for (int i = 0; i < 128; ++i) {
        float4 a = q[i], c = wq[i];
        s += a.x * c.x + a.y * c.y + a.z * c.z + a.w * c.w;
    }
    pq[t] = s;
}

// ---------------- main GEMM + fused epilogue ----------------
// 1024 blocks x 256 thr (4 waves, n-split). Block tile 64x512, wave 64x128.
// All-register K-loop: 4 A-frag + 8 B-frag coalesced loads per kt, 1-deep
// ping-pong, 32 MFMA per kt, no LDS, no barriers.
__global__ __launch_bounds__(256, 2) void gemm_kernel(
    const short* __restrict__ Abf, const short* __restrict__ Bsh,
    const float* __restrict__ pq, const float* __restrict__ v,
    float* __restrict__ pf, float* __restrict__ logits)
{
    __shared__ float uls[256];        // 64 rows x 4 waves (epilogue only)
    const int t    = threadIdx.x;
    const int lane = t & 63;
    const int w    = t >> 6;          // wave -> cols w*128..+128
    const int fm   = lane & 15;
    const int fkg  = lane >> 4;
    const int rb   = blockIdx.x;      // rows rb*64..+64

    const char* Ab = (const char*)Abf + (size_t)rb * 131072 + lane * 16;
    const char* Bb = (const char*)Bsh + (size_t)(w * 8 * 64 + lane) * 16;

    f32x4 acc[4][8];
    const f32x4 zf = {0.0f, 0.0f, 0.0f, 0.0f};
    #pragma unroll
    for (int f = 0; f < 4; ++f)
        #pragma unroll
        for (int g = 0; g < 8; ++g) acc[f][g] = zf;

    bf16x8 aX[4], aY[4], bX[8], bY[8];

    #define LOAD_A(DST, KT) do {                                             \
        _Pragma("unroll")                                                    \
        for (int f = 0; f < 4; ++f)                                          \
            DST[f] = *(const bf16x8*)(Ab + (((KT) & 31) * 4 + f) * 1024);    \
    } while (0)

    #define LOAD_B(DST, KT) do {                                             \
        const char* bk = Bb + (size_t)(((KT) & 31)) * 32768;                 \
        _Pragma("unroll")                                                    \
        for (int g = 0; g < 8; ++g)                                          \
            DST[g] = *(const bf16x8*)(bk + g * 1024);                        \
    } while (0)

    #define BODY(KT, AC, BC, AN, BN) do {                                    \
        LOAD_A(AN, (KT) + 1);                                                \
        LOAD_B(BN, (KT) + 1);                                                \
        _Pragma("unroll")                                                    \
        for (int f = 0; f < 4; ++f)                                          \
            _Pragma("unroll")                                                \
            for (int g = 0; g < 8; ++g)                                      \
                acc[f][g] = __builtin_amdgcn_mfma_f32_16x16x32_bf16(         \
                    AC[f], BC[g], acc[f][g], 0, 0, 0);                       \
    } while (0)

    LOAD_A(aX, 0);
    LOAD_B(bX, 0);

    #pragma unroll 1
    for (int kt2 = 0; kt2 < 16; ++kt2) {
        BODY(2 * kt2,     aX, bX, aY, bY);
        BODY(2 * kt2 + 1, aY, bY, aX, bX);
    }
    #undef LOAD_A
    #undef LOAD_B
    #undef BODY

    // ---- fused epilogue: pf store + u partials ----
    const int Mbase = rb * 64;
    const int bidx  = Mbase >> 12;
    const float* pqb = pq + (bidx << 9);
    float vv[8], pv[8];
    #pragma unroll
    for (int g = 0; g < 8; ++g) {
        const int c = w * 128 + g * 16 + fm;
        vv[g] = v[c];
        pv[g] = pqb[c];
    }
    #pragma unroll
    for (int f = 0; f < 4; ++f) {
        #pragma unroll
        for (int rr = 0; rr < 4; ++rr) {
            const int rloc = f * 16 + fkg * 4 + rr;
            float* prow = pf + (size_t)(Mbase + rloc) * HDIM + w * 128 + fm;
            float s = 0.0f;
            #pragma unroll
            for (int g = 0; g < 8; ++g) {
                const float val = acc[f][g][rr];
                __builtin_nontemporal_store(val, &prow[g * 16]);
                s += vv[g] * fast_tanh(val + pv[g]);
            }
            s += __shfl_xor(s, 1);
            s += __shfl_xor(s, 2);
            s += __shfl_xor(s, 4);
            s += __shfl_xor(s, 8);
            if (fm == 0) uls[rloc * 4 + w] = s;
        }
    }
    __syncthreads();
    if (t < 64) {
        const float4 p4 = *(const float4*)(uls + t * 4);
        const float u = p4.x + p4.y + p4.z + p4.w;
        logits[Mbase + t] = 10.0f * fast_tanh(u);
    }
}

extern "C" void kernel_launch(void* const* d_in, const int* in_sizes, int n_in,
                              void* d_out, int out_size, void* d_ws, size_t ws_size,
                              hipStream_t stream) {
    const float* features = (const float*)d_in[0];
    const float* query    = (const float*)d_in[1];
    const float* Wf       = (const float*)d_in[2];
    const float* Wq       = (const float*)d_in[3];
    const float* v        = (const float*)d_in[4];

    float* pf     = (float*)d_out;
    float* logits = (float*)d_out + 33554432;
    short* Abf    = (short*)d_out;                   // aliases pf region (see top)

    float* ws_pq  = (float*)d_ws;                    // 8192 f32  (32KB)
    short* ws_bsh = (short*)(ws_pq + 8192);          // 524288 bf16 (1MB)

    acvt_kernel<<<32768, 256, 0, stream>>>(features, Abf);
    bshuf_kernel<<<256, 256, 0, stream>>>(Wf, ws_bsh);
    pq_kernel<<<16, 512, 0, stream>>>(query, Wq, ws_pq);
    gemm_kernel<<<1024, 256, 0, stream>>>(Abf, ws_bsh, ws_pq, v, pf, logits);
}

// Round 8
// 184.723 us; speedup vs baseline: 1.2570x; 1.2570x over previous
//
#include <hip/hip_runtime.h>
#include <hip/hip_bf16.h>
#include <stdint.h>

// B=16, N=4096, H=512, K=2H=1024
//   pf[b,n,h]   = sum_k features[b,n,k] * Wf[h,k]
//   pq[b,h]     = sum_k query[b,k] * Wq[h,k]
//   logits[b,n] = 10*tanh( sum_h v[h]*tanh(pf+pq) )
// Outputs: pf (33554432 f32) then logits (65536 f32).
// R8: single-pass GEMM with queue-disciplined counted vmcnt.
//  Key fix vs R6/R7: per step issue B(kt) reg-loads FIRST, THEN gll A(kt+2).
//  -> compiler's B-wait = vmcnt(2) (never drains HBM gll's);
//  -> my vmcnt(10) waits exactly gll(kt+1) with >1 step slack;
//  -> one plain s_barrier/step bounds skew; 4-buffer LDS rotation race-free.
//  Tile 128x512 (A read once, fp32, cvt-on-read 1x/elem), 8 waves 2m x 4n,
//  wave 64x128, BK=32, 32 steps. B (Wf) pre-shuffled bf16 fragments in ws.

#define KDIM 1024
#define HDIM 512

typedef short bf16x8 __attribute__((ext_vector_type(8)));
typedef float f32x4  __attribute__((ext_vector_type(4)));

__device__ __forceinline__ float fast_tanh(float x) {
    float ax = fabsf(x);
    float e  = __expf(-2.0f * ax);
    float r  = (1.0f - e) / (1.0f + e);
    return copysignf(r, x);
}

__device__ __forceinline__ short f2bf(float x) {
    __hip_bfloat16 b = __float2bfloat16(x);
    return (short)__builtin_bit_cast(unsigned short, b);
}

__device__ __forceinline__ bf16x8 cvt8(float4 a, float4 b) {
    bf16x8 o;
    o[0] = f2bf(a.x); o[1] = f2bf(a.y); o[2] = f2bf(a.z); o[3] = f2bf(a.w);
    o[4] = f2bf(b.x); o[5] = f2bf(b.y); o[6] = f2bf(b.z); o[7] = f2bf(b.w);
    return o;
}

// ---------------- Wf -> bf16 B-fragment order (proven R4-R7) ----------------
// chunk tid = (kt*32 + gg)*64 + lane, lane = fkg*16+fm:
// content = Wf[gg*16+fm][kt*32 + fkg*8 .. +8] as bf16x8.
__global__ void bshuf_kernel(const float* __restrict__ Wf, short* __restrict__ Bsh) {
    const int tid = blockIdx.x * 256 + threadIdx.x;   // 0..65535
    const int kt  = tid >> 11;
    const int gg  = (tid >> 6) & 31;
    const int ln  = tid & 63;
    const int fm  = ln & 15, fkg = ln >> 4;
    const int col = gg * 16 + fm;
    const int k0  = kt * 32 + fkg * 8;
    const float* src = Wf + col * KDIM + k0;
    float4 a = *(const float4*)src;
    float4 b = *(const float4*)(src + 4);
    *(bf16x8*)(Bsh + (size_t)tid * 8) = cvt8(a, b);
}

// ---------------- tiny GEMM: pq[b,h] ----------------
__global__ void pq_kernel(const float* __restrict__ query,
                          const float* __restrict__ Wq,
                          float* __restrict__ pq) {
    const int t = blockIdx.x * blockDim.x + threadIdx.x;   // 8192
    const int b = t >> 9, h = t & 511;
    const float4* q  = (const float4*)(query + (b << 9));
    const float4* wq = (const float4*)(Wq + ((size_t)h << 9));
    float s = 0.0f;
    #pragma unroll 4
    for (int i = 0; i < 128; ++i) {
        float4 a = q[i], c = wq[i];
        s += a.x * c.x + a.y * c.y + a.z * c.z + a.w * c.w;
    }
    pq[t] = s;
}

// ---------------- main GEMM + fused epilogue ----------------
// 512 blocks x 512 thr (8 waves, 2m x 4n). Tile 128x512, wave 64x128, BK=32.
__global__ __launch_bounds__(512, 2) void gemm_kernel(
    const float* __restrict__ A, const short* __restrict__ Bsh,
    const float* __restrict__ pq, const float* __restrict__ v,
    float* __restrict__ pf, float* __restrict__ logits)
{
    __shared__ __align__(16) char ldsA[4][16384];   // 4-buf rotation, 128 rows x 128B
    __shared__ float uls[512];                      // 128 rows x 4 wn
    const int t    = threadIdx.x;
    const int lane = t & 63;
    const int w    = t >> 6;
    const int wm   = w >> 2;          // m half (rows wm*64..)
    const int wn   = w & 3;           // n quarter (cols wn*128..)
    const int fm   = lane & 15;
    const int fkg  = lane >> 4;
    const int Mbase = blockIdx.x * 128;

    // ---- A staging: chunk c = i*512+t; LDS(row,slot) = global(row, slot^(row&7))
    int asrc[2], adst[2];
    #pragma unroll
    for (int i = 0; i < 2; ++i) {
        const int c = i * 512 + t;
        const int row = c >> 3, slot = c & 7;
        asrc[i] = row * 4096 + ((slot ^ (row & 7)) << 4);
        adst[i] = c * 16;
    }
    const char* Ab = (const char*)(A + (size_t)Mbase * KDIM);

    // ---- A fragment ds_read offsets (swizzled): rows wm*64+f*16+fm ----
    int ard[4][2];
    #pragma unroll
    for (int f = 0; f < 4; ++f) {
        const int r = wm * 64 + f * 16 + fm;
        ard[f][0] = r * 128 + (((fkg * 2    ) ^ (r & 7)) << 4);
        ard[f][1] = r * 128 + (((fkg * 2 + 1) ^ (r & 7)) << 4);
    }

    // ---- B fragment base (fragment-order ws) ----
    const char* Bb = (const char*)Bsh + (size_t)((wn * 8 * 64) + lane) * 16;

    f32x4 acc[4][8];
    const f32x4 zf = {0.0f, 0.0f, 0.0f, 0.0f};
    #pragma unroll
    for (int f = 0; f < 4; ++f)
        #pragma unroll
        for (int g = 0; g < 8; ++g) acc[f][g] = zf;

    #define STAGE(BUF, KT) do {                                              \
        _Pragma("unroll")                                                    \
        for (int i = 0; i < 2; ++i)                                          \
            __builtin_amdgcn_global_load_lds(                                \
                (const __attribute__((address_space(1))) void*)              \
                    (Ab + asrc[i] + ((KT) & 31) * 128),                      \
                (__attribute__((address_space(3))) void*)                    \
                    (&ldsA[BUF][adst[i]]), 16, 0, 0);                        \
    } while (0)

    // Per step kt: [B(kt) x8]  [gll A(kt+2) x2]  vmcnt(10)=wait gll(kt+1)
    // barrier  ds_read raw A(kt+1)  MFMA(A(kt),B(kt))  cvt->A(kt+1) regs.
    #define BODY(KT, AC, AN) do {                                            \
        bf16x8 bfr[8];                                                       \
        const char* bk = Bb + (size_t)(KT) * 32768;                          \
        _Pragma("unroll")                                                    \
        for (int g = 0; g < 8; ++g) bfr[g] = *(const bf16x8*)(bk + g * 1024);\
        asm volatile("" ::: "memory");   /* pin B-loads BEFORE the gll */    \
        STAGE(((KT) + 2) & 3, (KT) + 2);                                     \
        asm volatile("s_waitcnt vmcnt(10)" ::: "memory");                    \
        __builtin_amdgcn_s_barrier();                                        \
        asm volatile("" ::: "memory");                                       \
        const char* base = ldsA[((KT) + 1) & 3];                             \
        float4 ra[8];                                                        \
        _Pragma("unroll")                                                    \
        for (int f = 0; f < 4; ++f) {                                        \
            ra[2 * f]     = *(const float4*)(base + ard[f][0]);              \
            ra[2 * f + 1] = *(const float4*)(base + ard[f][1]);              \
        }                                                                    \
        _Pragma("unroll")                                                    \
        for (int f = 0; f < 4; ++f)                                          \
            _Pragma("unroll")                                                \
            for (int g = 0; g < 8; ++g)                                      \
                acc[f][g] = __builtin_amdgcn_mfma_f32_16x16x32_bf16(         \
                    AC[f], bfr[g], acc[f][g], 0, 0, 0);                      \
        _Pragma("unroll")                                                    \
        for (int f = 0; f < 4; ++f) AN[f] = cvt8(ra[2 * f], ra[2 * f + 1]);  \
    } while (0)

    // ---- prologue: stage A(0),A(1); read A(0) into regs ----
    STAGE(0, 0);
    STAGE(1, 1);
    asm volatile("s_waitcnt vmcnt(2)" ::: "memory");   // gll(0) landed
    __builtin_amdgcn_s_barrier();
    asm volatile("" ::: "memory");
    bf16x8 aX[4], aY[4];
    {
        const char* base = ldsA[0];
        float4 ra[8];
        #pragma unroll
        for (int f = 0; f < 4; ++f) {
            ra[2 * f]     = *(const float4*)(base + ard[f][0]);
            ra[2 * f + 1] = *(const float4*)(base + ard[f][1]);
        }
        #pragma unroll
        for (int f = 0; f < 4; ++f) aX[f] = cvt8(ra[2 * f], ra[2 * f + 1]);
    }

    #pragma unroll 1
    for (int kt2 = 0; kt2 < 16; ++kt2) {
        BODY(2 * kt2,     aX, aY);
        BODY(2 * kt2 + 1, aY, aX);
    }
    #undef BODY
    #undef STAGE

    // ---- fused epilogue: pf store + u partials ----
    const int bidx = Mbase >> 12;
    const float* pqb = pq + (bidx << 9);
    float vv[8], pv[8];
    #pragma unroll
    for (int g = 0; g < 8; ++g) {
        const int c = wn * 128 + g * 16 + fm;
        vv[g] = v[c];
        pv[g] = pqb[c];
    }
    #pragma unroll
    for (int f = 0; f < 4; ++f) {
        #pragma unroll
        for (int rr = 0; rr < 4; ++rr) {
            const int rloc = wm * 64 + f * 16 + fkg * 4 + rr;
            float* prow = pf + (size_t)(Mbase + rloc) * HDIM + wn * 128 + fm;
            float s = 0.0f;
            #pragma unroll
            for (int g = 0; g < 8; ++g) {
                const float val = acc[f][g][rr];
                __builtin_nontemporal_store(val, &prow[g * 16]);
                s += vv[g] * fast_tanh(val + pv[g]);
            }
            s += __shfl_xor(s, 1);
            s += __shfl_xor(s, 2);
            s += __shfl_xor(s, 4);
            s += __shfl_xor(s, 8);
            if (fm == 0) uls[rloc * 4 + wn] = s;
        }
    }
    __syncthreads();
    if (t < 128) {
        const float4 p4 = *(const float4*)(uls + t * 4);
        const float u = p4.x + p4.y + p4.z + p4.w;
        logits[Mbase + t] = 10.0f * fast_tanh(u);
    }
}

extern "C" void kernel_launch(void* const* d_in, const int* in_sizes, int n_in,
                              void* d_out, int out_size, void* d_ws, size_t ws_size,
                              hipStream_t stream) {
    const float* features = (const float*)d_in[0];
    const float* query    = (const float*)d_in[1];
    const float* Wf       = (const float*)d_in[2];
    const float* Wq       = (const float*)d_in[3];
    const float* v        = (const float*)d_in[4];

    float* pf     = (float*)d_out;
    float* logits = (float*)d_out + 33554432;

    float* ws_pq  = (float*)d_ws;                    // 8192 f32  (32KB)
    short* ws_bsh = (short*)(ws_pq + 8192);          // 524288 bf16 (1MB)

    bshuf_kernel<<<256, 256, 0, stream>>>(Wf, ws_bsh);
    pq_kernel<<<16, 512, 0, stream>>>(query, Wq, ws_pq);
    gemm_kernel<<<512, 512, 0, stream>>>(features, ws_bsh, ws_pq, v, pf, logits);
}